// Round 5
// baseline (2952.635 us; speedup 1.0000x reference)
//
#include <hip/hip_runtime.h>

#define NN 16384
#define DD 16
#define KK 64
#define CAND_MAX 1024

// XLA:CPU vectorized row-reduce, minor dim 16: lane halving tree.
// p[d] = v[d]*v[d] (unfused); r8[j]=p[j]+p[j+8]; r4[j]=r8[j]+r8[j+4];
// r2[j]=r4[j]+r4[j+2]; res = r2[0]+r2[1].  All f32, round-to-nearest.
__device__ __forceinline__ float halving_sumsq16(const float* v) {
    float p[16];
#pragma unroll
    for (int d = 0; d < 16; ++d) p[d] = __fmul_rn(v[d], v[d]);
    float r8[8];
#pragma unroll
    for (int j = 0; j < 8; ++j) r8[j] = __fadd_rn(p[j], p[j + 8]);
    float r4[4];
#pragma unroll
    for (int j = 0; j < 4; ++j) r4[j] = __fadd_rn(r8[j], r8[j + 4]);
    float r2[2];
#pragma unroll
    for (int j = 0; j < 2; ++j) r2[j] = __fadd_rn(r4[j], r4[j + 2]);
    return __fadd_rn(r2[0], r2[1]);
}

// ---------------- prep: f32 squared norms (halving tree) + copy x ----------------
__global__ void prep_kernel(const float* __restrict__ x,
                            float* __restrict__ out_x,
                            float* __restrict__ sqf) {
    int i = blockIdx.x * blockDim.x + threadIdx.x;
    if (i < NN) {
        float v[DD];
#pragma unroll
        for (int d = 0; d < DD; ++d) v[d] = x[i * DD + d];
        sqf[i] = halving_sumsq16(v);
    }
    for (int t = i; t < NN * DD; t += gridDim.x * blockDim.x) {
        out_x[t] = x[t];
    }
}

// ---------------- main: per-node exact top-K ----------------
__global__ __launch_bounds__(256) void knn_kernel(
        const float* __restrict__ x,
        const int* __restrict__ pid,
        const float* __restrict__ sqf,
        float* __restrict__ out_src,
        float* __restrict__ out_dst,
        float* __restrict__ out_y,
        float* __restrict__ out_ef,
        float* __restrict__ out_mask) {
    __shared__ unsigned int keys[NN];        // 64 KB
    __shared__ unsigned int hist[256];
    __shared__ int cand_idx[CAND_MAX];
    __shared__ unsigned int cand_key[CAND_MAX];
    __shared__ float xi_s[DD];
    __shared__ unsigned int s_pref, s_need, s_cnt;

    const int i = blockIdx.x;
    const int tid = threadIdx.x;

    if (tid < DD) xi_s[tid] = x[i * DD + tid];
    if (tid == 0) s_cnt = 0;
    __syncthreads();

    float xi[DD];
#pragma unroll
    for (int d = 0; d < DD; ++d) xi[d] = xi_s[d];
    const float sqi = sqf[i];

    // ---- phase 1: f32 d2 -> monotone u32 keys ----
    // d2 = f32( f32(sqi + sqj) - 2*dot ), dot = ascending-k fused-FMA chain
    // (Eigen/oneDNN gemm: zeroed acc, sequential k, single accumulator)
    for (int j = tid; j < NN; j += 256) {
        const float4* xj4 = reinterpret_cast<const float4*>(x + j * DD);
        float4 a0 = xj4[0], a1 = xj4[1], a2 = xj4[2], a3 = xj4[3];
        float xj[DD] = {a0.x, a0.y, a0.z, a0.w, a1.x, a1.y, a1.z, a1.w,
                        a2.x, a2.y, a2.z, a2.w, a3.x, a3.y, a3.z, a3.w};
        float dot = 0.0f;
#pragma unroll
        for (int d = 0; d < DD; ++d) dot = fmaf(xi[d], xj[d], dot);
        float t1 = __fadd_rn(sqi, sqf[j]);
        float d2 = __fsub_rn(t1, __fmul_rn(2.0f, dot));
        unsigned int u = __float_as_uint(d2);
        u ^= (u & 0x80000000u) ? 0xFFFFFFFFu : 0x80000000u;  // order-preserving map
        if (j == i) u = 0xFFFFFFFFu;                         // exclude self
        keys[j] = u;
    }
    __syncthreads();

    // ---- phase 2: 4-pass radix histogram -> exact 64th-smallest key ----
    unsigned int pref = 0;
    unsigned int need = KK;
    for (int p = 0; p < 4; ++p) {
        const int shift = 24 - 8 * p;
        for (int b = tid; b < 256; b += 256) hist[b] = 0;
        __syncthreads();
        for (int j = tid; j < NN; j += 256) {
            unsigned int u = keys[j];
            if (((u >> shift) >> 8) == pref)
                atomicAdd(&hist[(u >> shift) & 0xFFu], 1u);
        }
        __syncthreads();
        if (tid == 0) {
            unsigned int cum = 0, t = 0;
            for (; t < 255; ++t) {
                if (cum + hist[t] >= need) break;
                cum += hist[t];
            }
            s_pref = (pref << 8) | t;
            s_need = need - cum;
        }
        __syncthreads();
        pref = s_pref;
        need = s_need;
        __syncthreads();
    }
    const unsigned int v64 = pref;

    // ---- phase 3: gather candidates (all keys <= v64, superset of top-64) ----
    for (int j = tid; j < NN; j += 256) {
        unsigned int u = keys[j];
        if (u <= v64) {
            unsigned int pos = atomicAdd(&s_cnt, 1u);
            if (pos < CAND_MAX) {
                cand_idx[pos] = j;
                cand_key[pos] = u;
            }
        }
    }
    __syncthreads();
    int c = (int)s_cnt;
    if (c > CAND_MAX) c = CAND_MAX;

    // ---- phase 4: rank by (key asc, index asc) [TopK tie semantics] + write ----
    const int mypid = pid[i];
    for (int t = tid; t < c; t += 256) {
        const unsigned int kt = cand_key[t];
        const int jt = cand_idx[t];
        int rank = 0;
        for (int u = 0; u < c; ++u) {
            unsigned int ku = cand_key[u];
            rank += (ku < kt) || (ku == kt && cand_idx[u] < jt);
        }
        if (rank < KK) {
            const long e = (long)i * KK + rank;
            out_src[e] = (float)jt;

            const float* xj = x + jt * DD;
            float diff[DD], sum[DD];
#pragma unroll
            for (int d = 0; d < DD; ++d) {
                float a = xj[d], b = xi_s[d];
                diff[d] = __fsub_rn(a, b);   // x_src - x_dst
                sum[d]  = __fadd_rn(a, b);   // x_src + x_dst
            }
            const float s2 = halving_sumsq16(diff);    // same reduce tree
            const bool m = __fsqrt_rn(s2) < 6.0f;      // correctly-rounded sqrt
            out_mask[e] = m ? 1.0f : 0.0f;
            const int pj = pid[jt];
            out_y[e] = (m && pj == mypid && pj > 0) ? 1.0f : 0.0f;

            float* ef = out_ef + e * (2 * DD);
#pragma unroll
            for (int d = 0; d < DD; ++d) ef[d] = m ? diff[d] : 0.0f;
#pragma unroll
            for (int d = 0; d < DD; ++d) ef[DD + d] = m ? sum[d] : 0.0f;
        }
    }

    // dst column of edge_index: all K entries = i
    for (int t = tid; t < KK; t += 256) {
        out_dst[(long)i * KK + t] = (float)i;
    }
}

extern "C" void kernel_launch(void* const* d_in, const int* in_sizes, int n_in,
                              void* d_out, int out_size, void* d_ws, size_t ws_size,
                              hipStream_t stream) {
    const float* x = (const float*)d_in[0];
    const int* pid = (const int*)d_in[1];
    float* out = (float*)d_out;

    float* out_x   = out;                                // N*D
    float* out_src = out_x + NN * DD;                    // N*K
    float* out_dst = out_src + NN * KK;                  // N*K
    float* out_y   = out_dst + NN * KK;                  // N*K
    float* out_ef  = out_y + NN * KK;                    // N*K*2D
    float* out_mask = out_ef + (long)NN * KK * 2 * DD;   // N*K

    float* sqf = (float*)d_ws;                           // 16384 f32 = 64 KB

    prep_kernel<<<NN / 256, 256, 0, stream>>>(x, out_x, sqf);
    knn_kernel<<<NN, 256, 0, stream>>>(x, pid, sqf, out_src, out_dst, out_y,
                                       out_ef, out_mask);
}